// Round 2
// baseline (251.825 us; speedup 1.0000x reference)
//
#include <hip/hip_runtime.h>
#include <hip/hip_bf16.h>
#include <math.h>

#define BLOCK 256
#define ITEMS 8
#define TILE (BLOCK * ITEMS)

__device__ __forceinline__ float compute_ratio(const float* uw, const int* timep) {
  int t = timep[0];
  t = ((t % 4) + 4) % 4;
  float base = (t == 0) ? 0.5f : (t == 1) ? 0.3f : (t == 2) ? 0.7f : 0.2f;
  double u = (double)uw[0];
  float w = (float)(-log1p(-u));  // SCALE=1, CONCENTRATION=1
  float r = base * w;
  r = fminf(fmaxf(r, 0.0f), 0.9f);
  if (r < 0.1f) r = 0.0f;
  return r;
}

// Detect whether rec/send are int64 (odd 32-bit words all zero) or int32.
// Writes flag (1 = int64, 0 = int32) to flagp[0]. Deterministic: data-fixed.
__global__ __launch_bounds__(64) void detect_i64(
    const unsigned* __restrict__ rec32, const unsigned* __restrict__ send32,
    unsigned* __restrict__ flagp) {
  const int tid = threadIdx.x;
  unsigned acc = 0;
#pragma unroll
  for (int j = 0; j < 4; ++j) {
    const int i = tid + j * 64;             // entries 0..255
    acc |= rec32[2 * i + 1];                // odd words (high half if int64)
    acc |= send32[2 * i + 1];
  }
#pragma unroll
  for (int d = 1; d < 64; d <<= 1) acc |= __shfl_xor(acc, d);
  if (tid == 0) flagp[0] = (acc == 0u) ? 1u : 0u;
}

// Pass A: per-block count of active edges
__global__ __launch_bounds__(BLOCK) void passA(
    const float* __restrict__ aedges, const float* __restrict__ ue,
    const float* __restrict__ uw, const int* __restrict__ timep,
    unsigned* __restrict__ bsums, int E) {
  __shared__ float s_ratio;
  __shared__ unsigned s_w[BLOCK / 64];
  const int tid = threadIdx.x;
  if (tid == 0) s_ratio = compute_ratio(uw, timep);
  __syncthreads();
  const float ratio = s_ratio;
  const long long base = (long long)blockIdx.x * TILE + (long long)tid * ITEMS;
  unsigned c = 0;
  if (base + ITEMS <= (long long)E) {
    const float4 a0 = *(const float4*)(aedges + base);
    const float4 a1 = *(const float4*)(aedges + base + 4);
    const float4 u0 = *(const float4*)(ue + base);
    const float4 u1 = *(const float4*)(ue + base + 4);
    const float av[8] = {a0.x, a0.y, a0.z, a0.w, a1.x, a1.y, a1.z, a1.w};
    const float uv[8] = {u0.x, u0.y, u0.z, u0.w, u1.x, u1.y, u1.z, u1.w};
#pragma unroll
    for (int j = 0; j < 8; ++j) c += (av[j] != 0.0f && uv[j] >= ratio) ? 1u : 0u;
  } else {
    for (int j = 0; j < 8; ++j) {
      long long i = base + j;
      if (i < (long long)E) c += (aedges[i] != 0.0f && ue[i] >= ratio) ? 1u : 0u;
    }
  }
#pragma unroll
  for (int d = 1; d < 64; d <<= 1) c += __shfl_xor(c, d);
  if ((tid & 63) == 0) s_w[tid >> 6] = c;
  __syncthreads();
  if (tid == 0) bsums[blockIdx.x] = s_w[0] + s_w[1] + s_w[2] + s_w[3];
}

// Pass B: exclusive scan of block sums (single block), total at bsums[nblocks]
__global__ __launch_bounds__(BLOCK) void passB(unsigned* __restrict__ bsums, int nblocks) {
  __shared__ unsigned s_w[BLOCK / 64];
  __shared__ unsigned s_carry;
  const int tid = threadIdx.x;
  if (tid == 0) s_carry = 0u;
  __syncthreads();
  for (int start = 0; start < nblocks; start += BLOCK) {
    const int idx = start + tid;
    const unsigned v = (idx < nblocks) ? bsums[idx] : 0u;
    unsigned x = v;
#pragma unroll
    for (int d = 1; d < 64; d <<= 1) {
      unsigned t = __shfl_up(x, d);
      if ((tid & 63) >= d) x += t;
    }
    if ((tid & 63) == 63) s_w[tid >> 6] = x;
    __syncthreads();
    unsigned woff = 0;
    for (int w = 0; w < (tid >> 6); ++w) woff += s_w[w];
    const unsigned carry = s_carry;
    __syncthreads();
    if (idx < nblocks) bsums[idx] = carry + woff + (x - v);
    if (tid == BLOCK - 1) s_carry = carry + woff + x;
    __syncthreads();
  }
  if (tid == 0) bsums[nblocks] = s_carry;
}

// Pass C: recompute flags, scan within block, scatter all outputs (float32)
__global__ __launch_bounds__(BLOCK) void passC(
    const float* __restrict__ aedges, const float* __restrict__ ue,
    const float* __restrict__ uw, const int* __restrict__ timep,
    const int* __restrict__ rec32, const int* __restrict__ send32,
    const float* __restrict__ edges,
    const unsigned* __restrict__ bsums, int nblocks,
    const unsigned* __restrict__ flagp,
    float* __restrict__ out, int E, int sentinel) {
  __shared__ float s_ratio;
  __shared__ unsigned s_w[BLOCK / 64];
  __shared__ unsigned s_i64;
  const int tid = threadIdx.x;
  if (tid == 0) { s_ratio = compute_ratio(uw, timep); s_i64 = flagp[0]; }
  __syncthreads();
  const float ratio = s_ratio;
  const bool is64 = (s_i64 != 0u);
  const long long base = (long long)blockIdx.x * TILE + (long long)tid * ITEMS;
  unsigned m = 0;
  float av[8];
  if (base + ITEMS <= (long long)E) {
    const float4 a0 = *(const float4*)(aedges + base);
    const float4 a1 = *(const float4*)(aedges + base + 4);
    const float4 u0 = *(const float4*)(ue + base);
    const float4 u1 = *(const float4*)(ue + base + 4);
    av[0] = a0.x; av[1] = a0.y; av[2] = a0.z; av[3] = a0.w;
    av[4] = a1.x; av[5] = a1.y; av[6] = a1.z; av[7] = a1.w;
    const float uv[8] = {u0.x, u0.y, u0.z, u0.w, u1.x, u1.y, u1.z, u1.w};
#pragma unroll
    for (int j = 0; j < 8; ++j)
      if (av[j] != 0.0f && uv[j] >= ratio) m |= (1u << j);
  } else {
#pragma unroll
    for (int j = 0; j < 8; ++j) {
      long long i = base + j;
      av[j] = 0.0f;
      if (i < (long long)E) {
        av[j] = aedges[i];
        if (av[j] != 0.0f && ue[i] >= ratio) m |= (1u << j);
      }
    }
  }
  const unsigned c = __popc(m);
  unsigned x = c;
#pragma unroll
  for (int d = 1; d < 64; d <<= 1) {
    unsigned t = __shfl_up(x, d);
    if ((tid & 63) >= d) x += t;
  }
  if ((tid & 63) == 63) s_w[tid >> 6] = x;
  __syncthreads();
  unsigned woff = 0;
  for (int w = 0; w < (tid >> 6); ++w) woff += s_w[w];
  const unsigned thread_excl = bsums[blockIdx.x] + woff + (x - c);
  const unsigned nA = bsums[nblocks];

  float* __restrict__ out_na = out;
  float* __restrict__ out_rec = out + (size_t)E;
  float* __restrict__ out_send = out + 2 * (size_t)E;
  float* __restrict__ out_edges = out + 3 * (size_t)E;

#pragma unroll
  for (int j = 0; j < 8; ++j) {
    const long long i = base + j;
    if (i >= (long long)E) break;
    const bool act = ((m >> j) & 1u) != 0u;
    const unsigned rb = __popc(m & ((1u << j) - 1u));
    const unsigned actsBefore = thread_excl + rb;  // # active edges before i, globally
    const unsigned p = act ? actsBefore : (nA + (unsigned)((unsigned long long)i - actsBefore));

    out_na[p] = act ? av[j] : 0.0f;
    int rv = sentinel, sv = sentinel;
    if (act) {
      if (is64) {
        rv = (int)((const long long*)rec32)[i];
        sv = (int)((const long long*)send32)[i];
      } else {
        rv = rec32[i];
        sv = send32[i];
      }
    }
    out_rec[p] = (float)rv;
    out_send[p] = (float)sv;

    float4 e0, e1, e2, e3;
    if (act) {
      const float4* er = (const float4*)(edges + (size_t)i * 16);
      e0 = er[0]; e1 = er[1]; e2 = er[2]; e3 = er[3];
    } else {
      e0 = e1 = e2 = e3 = make_float4(0.f, 0.f, 0.f, 0.f);
    }
    float4* dst = (float4*)(out_edges + (size_t)p * 16);
    dst[0] = e0; dst[1] = e1; dst[2] = e2; dst[3] = e3;
  }
}

extern "C" void kernel_launch(void* const* d_in, const int* in_sizes, int n_in,
                              void* d_out, int out_size, void* d_ws, size_t ws_size,
                              hipStream_t stream) {
  const float* edges = (const float*)d_in[1];
  const float* aedges = (const float*)d_in[2];
  const float* uw = (const float*)d_in[3];
  const float* ue = (const float*)d_in[4];
  const int* rec = (const int*)d_in[5];
  const int* send = (const int*)d_in[6];
  const int* timep = (const int*)d_in[7];

  const int E = in_sizes[2];
  const int n_nodes = in_sizes[0] / 128;
  const int sentinel = n_nodes - 1;
  const int nblocks = (E + TILE - 1) / TILE;

  unsigned* bsums = (unsigned*)d_ws;            // nblocks + 1 uints
  unsigned* flagp = bsums + (nblocks + 2);      // dtype flag
  float* out = (float*)d_out;

  hipLaunchKernelGGL(detect_i64, dim3(1), dim3(64), 0, stream,
                     (const unsigned*)rec, (const unsigned*)send, flagp);
  hipLaunchKernelGGL(passA, dim3(nblocks), dim3(BLOCK), 0, stream,
                     aedges, ue, uw, timep, bsums, E);
  hipLaunchKernelGGL(passB, dim3(1), dim3(BLOCK), 0, stream, bsums, nblocks);
  hipLaunchKernelGGL(passC, dim3(nblocks), dim3(BLOCK), 0, stream,
                     aedges, ue, uw, timep, rec, send, edges, bsums, nblocks,
                     flagp, out, E, sentinel);
}

// Round 3
// 148.411 us; speedup vs baseline: 1.6968x; 1.6968x over previous
//
#include <hip/hip_runtime.h>
#include <hip/hip_bf16.h>
#include <math.h>

#define BLOCK 256
#define ITEMS 8
#define TILE (BLOCK * ITEMS)

__device__ __forceinline__ float compute_ratio(const float* uw, const int* timep) {
  int t = timep[0];
  t = ((t % 4) + 4) % 4;
  float base = (t == 0) ? 0.5f : (t == 1) ? 0.3f : (t == 2) ? 0.7f : 0.2f;
  double u = (double)uw[0];
  float w = (float)(-log1p(-u));  // SCALE=1, CONCENTRATION=1
  float r = base * w;
  r = fminf(fmaxf(r, 0.0f), 0.9f);
  if (r < 0.1f) r = 0.0f;
  return r;
}

// Detect whether rec/send are int64 (odd 32-bit words all zero) or int32.
__global__ __launch_bounds__(64) void detect_i64(
    const unsigned* __restrict__ rec32, const unsigned* __restrict__ send32,
    unsigned* __restrict__ flagp) {
  const int tid = threadIdx.x;
  unsigned acc = 0;
#pragma unroll
  for (int j = 0; j < 4; ++j) {
    const int i = tid + j * 64;
    acc |= rec32[2 * i + 1];
    acc |= send32[2 * i + 1];
  }
#pragma unroll
  for (int d = 1; d < 64; d <<= 1) acc |= __shfl_xor(acc, d);
  if (tid == 0) flagp[0] = (acc == 0u) ? 1u : 0u;
}

// Pass A: per-block count of active edges
__global__ __launch_bounds__(BLOCK) void passA(
    const float* __restrict__ aedges, const float* __restrict__ ue,
    const float* __restrict__ uw, const int* __restrict__ timep,
    unsigned* __restrict__ bsums, int E) {
  __shared__ float s_ratio;
  __shared__ unsigned s_w[BLOCK / 64];
  const int tid = threadIdx.x;
  if (tid == 0) s_ratio = compute_ratio(uw, timep);
  __syncthreads();
  const float ratio = s_ratio;
  const long long base = (long long)blockIdx.x * TILE + (long long)tid * ITEMS;
  unsigned c = 0;
  if (base + ITEMS <= (long long)E) {
    const float4 a0 = *(const float4*)(aedges + base);
    const float4 a1 = *(const float4*)(aedges + base + 4);
    const float4 u0 = *(const float4*)(ue + base);
    const float4 u1 = *(const float4*)(ue + base + 4);
    const float av[8] = {a0.x, a0.y, a0.z, a0.w, a1.x, a1.y, a1.z, a1.w};
    const float uv[8] = {u0.x, u0.y, u0.z, u0.w, u1.x, u1.y, u1.z, u1.w};
#pragma unroll
    for (int j = 0; j < 8; ++j) c += (av[j] != 0.0f && uv[j] >= ratio) ? 1u : 0u;
  } else {
    for (int j = 0; j < 8; ++j) {
      long long i = base + j;
      if (i < (long long)E) c += (aedges[i] != 0.0f && ue[i] >= ratio) ? 1u : 0u;
    }
  }
#pragma unroll
  for (int d = 1; d < 64; d <<= 1) c += __shfl_xor(c, d);
  if ((tid & 63) == 0) s_w[tid >> 6] = c;
  __syncthreads();
  if (tid == 0) bsums[blockIdx.x] = s_w[0] + s_w[1] + s_w[2] + s_w[3];
}

// Pass B: exclusive scan of block sums (single block), total at bsums[nblocks]
__global__ __launch_bounds__(BLOCK) void passB(unsigned* __restrict__ bsums, int nblocks) {
  __shared__ unsigned s_w[BLOCK / 64];
  __shared__ unsigned s_carry;
  const int tid = threadIdx.x;
  if (tid == 0) s_carry = 0u;
  __syncthreads();
  for (int start = 0; start < nblocks; start += BLOCK) {
    const int idx = start + tid;
    const unsigned v = (idx < nblocks) ? bsums[idx] : 0u;
    unsigned x = v;
#pragma unroll
    for (int d = 1; d < 64; d <<= 1) {
      unsigned t = __shfl_up(x, d);
      if ((tid & 63) >= d) x += t;
    }
    if ((tid & 63) == 63) s_w[tid >> 6] = x;
    __syncthreads();
    unsigned woff = 0;
    for (int w = 0; w < (tid >> 6); ++w) woff += s_w[w];
    const unsigned carry = s_carry;
    __syncthreads();
    if (idx < nblocks) bsums[idx] = carry + woff + (x - v);
    if (tid == BLOCK - 1) s_carry = carry + woff + x;
    __syncthreads();
  }
  if (tid == 0) bsums[nblocks] = s_carry;
}

// Pass C: rank permutation in LDS, then DEST-ORDERED coalesced writes.
// Each block's outputs are two contiguous ranges (active chunk / inactive chunk).
__global__ __launch_bounds__(BLOCK) void passC(
    const float* __restrict__ aedges, const float* __restrict__ ue,
    const float* __restrict__ uw, const int* __restrict__ timep,
    const int* __restrict__ rec32, const int* __restrict__ send32,
    const float* __restrict__ edges,
    const unsigned* __restrict__ bsums, int nblocks,
    const unsigned* __restrict__ flagp,
    float* __restrict__ out, int E, int sentinel) {
  __shared__ float s_ratio;
  __shared__ unsigned s_w[BLOCK / 64];
  __shared__ unsigned s_i64;
  __shared__ unsigned short s_sidx[TILE];  // dest rank -> local source index
  __shared__ float s_na[TILE];             // dest rank -> naedges value
  const int tid = threadIdx.x;
  if (tid == 0) { s_ratio = compute_ratio(uw, timep); s_i64 = flagp[0]; }
  __syncthreads();
  const float ratio = s_ratio;
  const bool is64 = (s_i64 != 0u);
  const long long tileBase = (long long)blockIdx.x * TILE;
  const int local_n = (int)min((long long)TILE, (long long)E - tileBase);
  const long long base = tileBase + (long long)tid * ITEMS;

  // --- phase 1: flags + block scan + LDS permutation staging ---
  unsigned m = 0;
  float av[8];
  if (base + ITEMS <= (long long)E) {
    const float4 a0 = *(const float4*)(aedges + base);
    const float4 a1 = *(const float4*)(aedges + base + 4);
    const float4 u0 = *(const float4*)(ue + base);
    const float4 u1 = *(const float4*)(ue + base + 4);
    av[0] = a0.x; av[1] = a0.y; av[2] = a0.z; av[3] = a0.w;
    av[4] = a1.x; av[5] = a1.y; av[6] = a1.z; av[7] = a1.w;
    const float uv[8] = {u0.x, u0.y, u0.z, u0.w, u1.x, u1.y, u1.z, u1.w};
#pragma unroll
    for (int j = 0; j < 8; ++j)
      if (av[j] != 0.0f && uv[j] >= ratio) m |= (1u << j);
  } else {
#pragma unroll
    for (int j = 0; j < 8; ++j) {
      long long i = base + j;
      av[j] = 0.0f;
      if (i < (long long)E) {
        av[j] = aedges[i];
        if (av[j] != 0.0f && ue[i] >= ratio) m |= (1u << j);
      }
    }
  }
  const unsigned c = __popc(m);
  unsigned x = c;
#pragma unroll
  for (int d = 1; d < 64; d <<= 1) {
    unsigned t = __shfl_up(x, d);
    if ((tid & 63) >= d) x += t;
  }
  if ((tid & 63) == 63) s_w[tid >> 6] = x;
  __syncthreads();
  unsigned woff = 0;
  for (int w = 0; w < (tid >> 6); ++w) woff += s_w[w];
  const unsigned cnt = s_w[0] + s_w[1] + s_w[2] + s_w[3];  // block active count
  const unsigned thread_excl = woff + (x - c);             // local active rank base

#pragma unroll
  for (int j = 0; j < 8; ++j) {
    const int li = tid * ITEMS + j;
    if (li >= local_n) break;
    const bool act = ((m >> j) & 1u) != 0u;
    const unsigned rb = __popc(m & ((1u << j) - 1u));
    const unsigned actsBefore = thread_excl + rb;
    const unsigned dr = act ? actsBefore : (cnt + ((unsigned)li - actsBefore));
    s_sidx[dr] = (unsigned short)li;
    s_na[dr] = act ? av[j] : 0.0f;
  }
  __syncthreads();

  // --- phase 2: dest-ordered coalesced writes ---
  const unsigned gA = bsums[blockIdx.x];
  const unsigned nA = bsums[nblocks];
  const unsigned gI = nA + (unsigned)tileBase - gA;  // inactive chunk base
  const float sentf = (float)sentinel;

  float* __restrict__ out_na = out;
  float* __restrict__ out_rec = out + (size_t)E;
  float* __restrict__ out_send = out + 2 * (size_t)E;
  float* __restrict__ out_edges = out + 3 * (size_t)E;

#pragma unroll
  for (int k = 0; k < ITEMS; ++k) {
    const int r = tid + k * BLOCK;  // dest rank, unit-stride across lanes
    if (r >= local_n) break;
    const bool ra = (unsigned)r < cnt;
    const unsigned dest = ra ? (gA + (unsigned)r) : (gI + ((unsigned)r - cnt));
    const int si = (int)s_sidx[r];
    const long long gi = tileBase + si;

    out_na[dest] = s_na[r];
    float rv = sentf, sv = sentf;
    if (ra) {
      if (is64) {
        rv = (float)(int)((const long long*)rec32)[gi];
        sv = (float)(int)((const long long*)send32)[gi];
      } else {
        rv = (float)rec32[gi];
        sv = (float)send32[gi];
      }
    }
    out_rec[dest] = rv;
    out_send[dest] = sv;

    float4 e0, e1, e2, e3;
    if (ra) {
      const float4* er = (const float4*)(edges + (size_t)gi * 16);
      e0 = er[0]; e1 = er[1]; e2 = er[2]; e3 = er[3];
    } else {
      e0 = e1 = e2 = e3 = make_float4(0.f, 0.f, 0.f, 0.f);
    }
    float4* dst = (float4*)(out_edges + (size_t)dest * 16);
    dst[0] = e0; dst[1] = e1; dst[2] = e2; dst[3] = e3;
  }
}

extern "C" void kernel_launch(void* const* d_in, const int* in_sizes, int n_in,
                              void* d_out, int out_size, void* d_ws, size_t ws_size,
                              hipStream_t stream) {
  const float* edges = (const float*)d_in[1];
  const float* aedges = (const float*)d_in[2];
  const float* uw = (const float*)d_in[3];
  const float* ue = (const float*)d_in[4];
  const int* rec = (const int*)d_in[5];
  const int* send = (const int*)d_in[6];
  const int* timep = (const int*)d_in[7];

  const int E = in_sizes[2];
  const int n_nodes = in_sizes[0] / 128;
  const int sentinel = n_nodes - 1;
  const int nblocks = (E + TILE - 1) / TILE;

  unsigned* bsums = (unsigned*)d_ws;
  unsigned* flagp = bsums + (nblocks + 2);
  float* out = (float*)d_out;

  hipLaunchKernelGGL(detect_i64, dim3(1), dim3(64), 0, stream,
                     (const unsigned*)rec, (const unsigned*)send, flagp);
  hipLaunchKernelGGL(passA, dim3(nblocks), dim3(BLOCK), 0, stream,
                     aedges, ue, uw, timep, bsums, E);
  hipLaunchKernelGGL(passB, dim3(1), dim3(BLOCK), 0, stream, bsums, nblocks);
  hipLaunchKernelGGL(passC, dim3(nblocks), dim3(BLOCK), 0, stream,
                     aedges, ue, uw, timep, rec, send, edges, bsums, nblocks,
                     flagp, out, E, sentinel);
}

// Round 4
// 145.053 us; speedup vs baseline: 1.7361x; 1.0232x over previous
//
#include <hip/hip_runtime.h>
#include <hip/hip_bf16.h>
#include <math.h>

#define BLOCK 256
#define ITEMS 8
#define TILE (BLOCK * ITEMS)

__device__ __forceinline__ float compute_ratio(const float* uw, const int* timep) {
  int t = timep[0];
  t = ((t % 4) + 4) % 4;
  float base = (t == 0) ? 0.5f : (t == 1) ? 0.3f : (t == 2) ? 0.7f : 0.2f;
  double u = (double)uw[0];
  float w = (float)(-log1p(-u));  // SCALE=1, CONCENTRATION=1
  float r = base * w;
  r = fminf(fmaxf(r, 0.0f), 0.9f);
  if (r < 0.1f) r = 0.0f;
  return r;
}

// Detect whether rec/send are int64 (odd 32-bit words all zero) or int32.
__global__ __launch_bounds__(64) void detect_i64(
    const unsigned* __restrict__ rec32, const unsigned* __restrict__ send32,
    unsigned* __restrict__ flagp) {
  const int tid = threadIdx.x;
  unsigned acc = 0;
#pragma unroll
  for (int j = 0; j < 4; ++j) {
    const int i = tid + j * 64;
    acc |= rec32[2 * i + 1];
    acc |= send32[2 * i + 1];
  }
#pragma unroll
  for (int d = 1; d < 64; d <<= 1) acc |= __shfl_xor(acc, d);
  if (tid == 0) flagp[0] = (acc == 0u) ? 1u : 0u;
}

// Pass A: per-block count of active edges
__global__ __launch_bounds__(BLOCK) void passA(
    const float* __restrict__ aedges, const float* __restrict__ ue,
    const float* __restrict__ uw, const int* __restrict__ timep,
    unsigned* __restrict__ bsums, int E) {
  __shared__ float s_ratio;
  __shared__ unsigned s_w[BLOCK / 64];
  const int tid = threadIdx.x;
  if (tid == 0) s_ratio = compute_ratio(uw, timep);
  __syncthreads();
  const float ratio = s_ratio;
  const long long base = (long long)blockIdx.x * TILE + (long long)tid * ITEMS;
  unsigned c = 0;
  if (base + ITEMS <= (long long)E) {
    const float4 a0 = *(const float4*)(aedges + base);
    const float4 a1 = *(const float4*)(aedges + base + 4);
    const float4 u0 = *(const float4*)(ue + base);
    const float4 u1 = *(const float4*)(ue + base + 4);
    const float av[8] = {a0.x, a0.y, a0.z, a0.w, a1.x, a1.y, a1.z, a1.w};
    const float uv[8] = {u0.x, u0.y, u0.z, u0.w, u1.x, u1.y, u1.z, u1.w};
#pragma unroll
    for (int j = 0; j < 8; ++j) c += (av[j] != 0.0f && uv[j] >= ratio) ? 1u : 0u;
  } else {
    for (int j = 0; j < 8; ++j) {
      long long i = base + j;
      if (i < (long long)E) c += (aedges[i] != 0.0f && ue[i] >= ratio) ? 1u : 0u;
    }
  }
#pragma unroll
  for (int d = 1; d < 64; d <<= 1) c += __shfl_xor(c, d);
  if ((tid & 63) == 0) s_w[tid >> 6] = c;
  __syncthreads();
  if (tid == 0) bsums[blockIdx.x] = s_w[0] + s_w[1] + s_w[2] + s_w[3];
}

// Pass B: exclusive scan of block sums (single block), total at bsums[nblocks]
__global__ __launch_bounds__(BLOCK) void passB(unsigned* __restrict__ bsums, int nblocks) {
  __shared__ unsigned s_w[BLOCK / 64];
  __shared__ unsigned s_carry;
  const int tid = threadIdx.x;
  if (tid == 0) s_carry = 0u;
  __syncthreads();
  for (int start = 0; start < nblocks; start += BLOCK) {
    const int idx = start + tid;
    const unsigned v = (idx < nblocks) ? bsums[idx] : 0u;
    unsigned x = v;
#pragma unroll
    for (int d = 1; d < 64; d <<= 1) {
      unsigned t = __shfl_up(x, d);
      if ((tid & 63) >= d) x += t;
    }
    if ((tid & 63) == 63) s_w[tid >> 6] = x;
    __syncthreads();
    unsigned woff = 0;
    for (int w = 0; w < (tid >> 6); ++w) woff += s_w[w];
    const unsigned carry = s_carry;
    __syncthreads();
    if (idx < nblocks) bsums[idx] = carry + woff + (x - v);
    if (tid == BLOCK - 1) s_carry = carry + woff + x;
    __syncthreads();
  }
  if (tid == 0) bsums[nblocks] = s_carry;
}

// Pass C: stage scalar streams + rank permutation in LDS (coalesced source
// reads), then dest-ordered full-line writes. Edge rows move with a
// 4-lanes-per-row mapping so each wave store instr is 1 KB contiguous.
__global__ __launch_bounds__(BLOCK) void passC(
    const float* __restrict__ aedges, const float* __restrict__ ue,
    const float* __restrict__ uw, const int* __restrict__ timep,
    const int* __restrict__ rec32, const int* __restrict__ send32,
    const float* __restrict__ edges,
    const unsigned* __restrict__ bsums, int nblocks,
    const unsigned* __restrict__ flagp,
    float* __restrict__ out, int E, int sentinel) {
  __shared__ float s_ratio;
  __shared__ unsigned s_w[BLOCK / 64];
  __shared__ unsigned s_i64;
  __shared__ unsigned short s_sidx[TILE];  // dest rank -> local source index
  __shared__ float s_na[TILE];             // dest rank -> naedges value
  __shared__ float s_rec[TILE];            // dest rank -> rec value (float)
  __shared__ float s_send[TILE];           // dest rank -> send value (float)
  const int tid = threadIdx.x;
  if (tid == 0) { s_ratio = compute_ratio(uw, timep); s_i64 = flagp[0]; }
  __syncthreads();
  const float ratio = s_ratio;
  const bool is64 = (s_i64 != 0u);
  const long long tileBase = (long long)blockIdx.x * TILE;
  const int local_n = (int)min((long long)TILE, (long long)E - tileBase);
  const long long base = tileBase + (long long)tid * ITEMS;
  const float sentf = (float)sentinel;

  // --- phase 1: flags + block scan ---
  unsigned m = 0;
  float av[8];
  if (base + ITEMS <= (long long)E) {
    const float4 a0 = *(const float4*)(aedges + base);
    const float4 a1 = *(const float4*)(aedges + base + 4);
    const float4 u0 = *(const float4*)(ue + base);
    const float4 u1 = *(const float4*)(ue + base + 4);
    av[0] = a0.x; av[1] = a0.y; av[2] = a0.z; av[3] = a0.w;
    av[4] = a1.x; av[5] = a1.y; av[6] = a1.z; av[7] = a1.w;
    const float uv[8] = {u0.x, u0.y, u0.z, u0.w, u1.x, u1.y, u1.z, u1.w};
#pragma unroll
    for (int j = 0; j < 8; ++j)
      if (av[j] != 0.0f && uv[j] >= ratio) m |= (1u << j);
  } else {
#pragma unroll
    for (int j = 0; j < 8; ++j) {
      long long i = base + j;
      av[j] = 0.0f;
      if (i < (long long)E) {
        av[j] = aedges[i];
        if (av[j] != 0.0f && ue[i] >= ratio) m |= (1u << j);
      }
    }
  }
  const unsigned c = __popc(m);
  unsigned x = c;
#pragma unroll
  for (int d = 1; d < 64; d <<= 1) {
    unsigned t = __shfl_up(x, d);
    if ((tid & 63) >= d) x += t;
  }
  if ((tid & 63) == 63) s_w[tid >> 6] = x;
  __syncthreads();
  unsigned woff = 0;
  for (int w = 0; w < (tid >> 6); ++w) woff += s_w[w];
  const unsigned cnt = s_w[0] + s_w[1] + s_w[2] + s_w[3];  // block active count
  const unsigned thread_excl = woff + (x - c);             // local active rank base

  // --- phase 1b: stage sidx / na / rec / send at dest rank (LDS scatter;
  //               rec/send read here in SOURCE order = coalesced) ---
#pragma unroll
  for (int j = 0; j < 8; ++j) {
    const int li = tid * ITEMS + j;
    if (li >= local_n) break;
    const long long i = base + j;
    const bool act = ((m >> j) & 1u) != 0u;
    const unsigned rb = __popc(m & ((1u << j) - 1u));
    const unsigned actsBefore = thread_excl + rb;
    const unsigned dr = act ? actsBefore : (cnt + ((unsigned)li - actsBefore));
    float rv = sentf, sv = sentf;
    if (act) {
      if (is64) {
        rv = (float)(int)((const long long*)rec32)[i];
        sv = (float)(int)((const long long*)send32)[i];
      } else {
        rv = (float)rec32[i];
        sv = (float)send32[i];
      }
    }
    s_sidx[dr] = (unsigned short)li;
    s_na[dr] = act ? av[j] : 0.0f;
    s_rec[dr] = rv;
    s_send[dr] = sv;
  }
  __syncthreads();

  const unsigned gA = bsums[blockIdx.x];
  const unsigned nA = bsums[nblocks];
  const unsigned gI = nA + (unsigned)tileBase - gA;  // inactive chunk base

  float* __restrict__ out_na = out;
  float* __restrict__ out_rec = out + (size_t)E;
  float* __restrict__ out_send = out + 2 * (size_t)E;
  float* __restrict__ out_edges = out + 3 * (size_t)E;

  // --- phase 2a: scalar streams, unit-stride LDS read + unit-stride write ---
#pragma unroll
  for (int k = 0; k < ITEMS; ++k) {
    const int r = tid + k * BLOCK;
    if (r >= local_n) break;
    const bool ra = (unsigned)r < cnt;
    const unsigned dest = ra ? (gA + (unsigned)r) : (gI + ((unsigned)r - cnt));
    out_na[dest] = s_na[r];
    out_rec[dest] = s_rec[r];
    out_send[dest] = s_send[r];
  }

  // --- phase 2b: edge rows, 4 lanes per 64B row -> 1KB contiguous per instr ---
  const int sub = tid & 3;
#pragma unroll 4
  for (int k = 0; k < TILE / (BLOCK / 4); ++k) {  // 32 iterations
    const int r = (tid >> 2) + k * (BLOCK / 4);
    if (r >= local_n) break;
    const bool ra = (unsigned)r < cnt;
    const unsigned dest = ra ? (gA + (unsigned)r) : (gI + ((unsigned)r - cnt));
    float4 v = make_float4(0.f, 0.f, 0.f, 0.f);
    if (ra) {
      const int si = (int)s_sidx[r];
      v = ((const float4*)edges)[(size_t)(tileBase + si) * 4 + sub];
    }
    ((float4*)out_edges)[(size_t)dest * 4 + sub] = v;
  }
}

extern "C" void kernel_launch(void* const* d_in, const int* in_sizes, int n_in,
                              void* d_out, int out_size, void* d_ws, size_t ws_size,
                              hipStream_t stream) {
  const float* edges = (const float*)d_in[1];
  const float* aedges = (const float*)d_in[2];
  const float* uw = (const float*)d_in[3];
  const float* ue = (const float*)d_in[4];
  const int* rec = (const int*)d_in[5];
  const int* send = (const int*)d_in[6];
  const int* timep = (const int*)d_in[7];

  const int E = in_sizes[2];
  const int n_nodes = in_sizes[0] / 128;
  const int sentinel = n_nodes - 1;
  const int nblocks = (E + TILE - 1) / TILE;

  unsigned* bsums = (unsigned*)d_ws;
  unsigned* flagp = bsums + (nblocks + 2);
  float* out = (float*)d_out;

  hipLaunchKernelGGL(detect_i64, dim3(1), dim3(64), 0, stream,
                     (const unsigned*)rec, (const unsigned*)send, flagp);
  hipLaunchKernelGGL(passA, dim3(nblocks), dim3(BLOCK), 0, stream,
                     aedges, ue, uw, timep, bsums, E);
  hipLaunchKernelGGL(passB, dim3(1), dim3(BLOCK), 0, stream, bsums, nblocks);
  hipLaunchKernelGGL(passC, dim3(nblocks), dim3(BLOCK), 0, stream,
                     aedges, ue, uw, timep, rec, send, edges, bsums, nblocks,
                     flagp, out, E, sentinel);
}

// Round 5
// 111.800 us; speedup vs baseline: 2.2525x; 1.2974x over previous
//
#include <hip/hip_runtime.h>
#include <hip/hip_bf16.h>
#include <math.h>

#define BLOCK 256
#define ITEMS 8
#define TILE (BLOCK * ITEMS)

typedef float f4v __attribute__((ext_vector_type(4)));

__device__ __forceinline__ float compute_ratio(const float* uw, const int* timep) {
  int t = timep[0];
  t = ((t % 4) + 4) % 4;
  float base = (t == 0) ? 0.5f : (t == 1) ? 0.3f : (t == 2) ? 0.7f : 0.2f;
  double u = (double)uw[0];
  float w = (float)(-log1p(-u));  // SCALE=1, CONCENTRATION=1
  float r = base * w;
  r = fminf(fmaxf(r, 0.0f), 0.9f);
  if (r < 0.1f) r = 0.0f;
  return r;
}

// Detect whether rec/send are int64 (odd 32-bit words all zero) or int32.
__global__ __launch_bounds__(64) void detect_i64(
    const unsigned* __restrict__ rec32, const unsigned* __restrict__ send32,
    unsigned* __restrict__ flagp) {
  const int tid = threadIdx.x;
  unsigned acc = 0;
#pragma unroll
  for (int j = 0; j < 4; ++j) {
    const int i = tid + j * 64;
    acc |= rec32[2 * i + 1];
    acc |= send32[2 * i + 1];
  }
#pragma unroll
  for (int d = 1; d < 64; d <<= 1) acc |= __shfl_xor(acc, d);
  if (tid == 0) flagp[0] = (acc == 0u) ? 1u : 0u;
}

// Pass A: per-block active count + per-thread 8-bit activity mask
__global__ __launch_bounds__(BLOCK) void passA(
    const float* __restrict__ aedges, const float* __restrict__ ue,
    const float* __restrict__ uw, const int* __restrict__ timep,
    unsigned* __restrict__ bsums, unsigned char* __restrict__ masks,
    int use_masks, int E) {
  __shared__ float s_ratio;
  __shared__ unsigned s_w[BLOCK / 64];
  const int tid = threadIdx.x;
  if (tid == 0) s_ratio = compute_ratio(uw, timep);
  __syncthreads();
  const float ratio = s_ratio;
  const long long base = (long long)blockIdx.x * TILE + (long long)tid * ITEMS;
  unsigned m = 0;
  if (base + ITEMS <= (long long)E) {
    const f4v a0 = *(const f4v*)(aedges + base);
    const f4v a1 = *(const f4v*)(aedges + base + 4);
    const f4v u0 = *(const f4v*)(ue + base);
    const f4v u1 = *(const f4v*)(ue + base + 4);
    const float av[8] = {a0.x, a0.y, a0.z, a0.w, a1.x, a1.y, a1.z, a1.w};
    const float uv[8] = {u0.x, u0.y, u0.z, u0.w, u1.x, u1.y, u1.z, u1.w};
#pragma unroll
    for (int j = 0; j < 8; ++j)
      if (av[j] != 0.0f && uv[j] >= ratio) m |= (1u << j);
  } else {
    for (int j = 0; j < 8; ++j) {
      long long i = base + j;
      if (i < (long long)E && aedges[i] != 0.0f && ue[i] >= ratio) m |= (1u << j);
    }
  }
  if (use_masks) masks[(size_t)blockIdx.x * BLOCK + tid] = (unsigned char)m;
  unsigned c = __popc(m);
#pragma unroll
  for (int d = 1; d < 64; d <<= 1) c += __shfl_xor(c, d);
  if ((tid & 63) == 0) s_w[tid >> 6] = c;
  __syncthreads();
  if (tid == 0) bsums[blockIdx.x] = s_w[0] + s_w[1] + s_w[2] + s_w[3];
}

// Pass B: exclusive scan of block sums (single block), total at bsums[nblocks]
__global__ __launch_bounds__(BLOCK) void passB(unsigned* __restrict__ bsums, int nblocks) {
  __shared__ unsigned s_w[BLOCK / 64];
  __shared__ unsigned s_carry;
  const int tid = threadIdx.x;
  if (tid == 0) s_carry = 0u;
  __syncthreads();
  for (int start = 0; start < nblocks; start += BLOCK) {
    const int idx = start + tid;
    const unsigned v = (idx < nblocks) ? bsums[idx] : 0u;
    unsigned x = v;
#pragma unroll
    for (int d = 1; d < 64; d <<= 1) {
      unsigned t = __shfl_up(x, d);
      if ((tid & 63) >= d) x += t;
    }
    if ((tid & 63) == 63) s_w[tid >> 6] = x;
    __syncthreads();
    unsigned woff = 0;
    for (int w = 0; w < (tid >> 6); ++w) woff += s_w[w];
    const unsigned carry = s_carry;
    __syncthreads();
    if (idx < nblocks) bsums[idx] = carry + woff + (x - v);
    if (tid == BLOCK - 1) s_carry = carry + woff + x;
    __syncthreads();
  }
  if (tid == 0) bsums[nblocks] = s_carry;
}

// Pass C: mask -> block scan -> ushort LDS permutation -> dest-ordered NT writes.
// LDS ~12.5 KB so occupancy is wave-capped (8 blocks/CU), not LDS-capped.
__global__ __launch_bounds__(BLOCK) void passC(
    const float* __restrict__ aedges, const float* __restrict__ ue,
    const float* __restrict__ uw, const int* __restrict__ timep,
    const int* __restrict__ rec32, const int* __restrict__ send32,
    const float* __restrict__ edges,
    const unsigned* __restrict__ bsums, int nblocks,
    const unsigned* __restrict__ flagp,
    const unsigned char* __restrict__ masks, int use_masks,
    float* __restrict__ out, int E, int sentinel) {
  __shared__ float s_ratio;
  __shared__ unsigned s_w[BLOCK / 64];
  __shared__ unsigned s_i64;
  __shared__ unsigned short s_sidx[TILE];  // dest rank -> local source index
  __shared__ unsigned short s_rec[TILE];   // dest rank -> rec id (<65536)
  __shared__ unsigned short s_send[TILE];  // dest rank -> send id (<65536)
  const int tid = threadIdx.x;
  if (tid == 0) { s_ratio = compute_ratio(uw, timep); s_i64 = flagp[0]; }
  __syncthreads();
  const bool is64 = (s_i64 != 0u);
  const long long tileBase = (long long)blockIdx.x * TILE;
  const int local_n = (int)min((long long)TILE, (long long)E - tileBase);
  const long long base = tileBase + (long long)tid * ITEMS;
  const unsigned short sent16 = (unsigned short)sentinel;

  // --- phase 1: activity mask ---
  unsigned m = 0;
  if (use_masks) {
    m = (unsigned)masks[(size_t)blockIdx.x * BLOCK + tid];
  } else {
    const float ratio = s_ratio;
    if (base + ITEMS <= (long long)E) {
      const f4v a0 = *(const f4v*)(aedges + base);
      const f4v a1 = *(const f4v*)(aedges + base + 4);
      const f4v u0 = *(const f4v*)(ue + base);
      const f4v u1 = *(const f4v*)(ue + base + 4);
      const float av[8] = {a0.x, a0.y, a0.z, a0.w, a1.x, a1.y, a1.z, a1.w};
      const float uv[8] = {u0.x, u0.y, u0.z, u0.w, u1.x, u1.y, u1.z, u1.w};
#pragma unroll
      for (int j = 0; j < 8; ++j)
        if (av[j] != 0.0f && uv[j] >= ratio) m |= (1u << j);
    } else {
      for (int j = 0; j < 8; ++j) {
        long long i = base + j;
        if (i < (long long)E && aedges[i] != 0.0f && ue[i] >= ratio) m |= (1u << j);
      }
    }
  }

  // --- block scan of active counts ---
  const unsigned c = __popc(m);
  unsigned x = c;
#pragma unroll
  for (int d = 1; d < 64; d <<= 1) {
    unsigned t = __shfl_up(x, d);
    if ((tid & 63) >= d) x += t;
  }
  if ((tid & 63) == 63) s_w[tid >> 6] = x;
  __syncthreads();
  unsigned woff = 0;
  for (int w = 0; w < (tid >> 6); ++w) woff += s_w[w];
  const unsigned cnt = s_w[0] + s_w[1] + s_w[2] + s_w[3];
  const unsigned thread_excl = woff + (x - c);

  // --- phase 1b: stage sidx/rec/send at dest rank (source-order global reads) ---
#pragma unroll
  for (int j = 0; j < 8; ++j) {
    const int li = tid * ITEMS + j;
    if (li >= local_n) break;
    const long long i = base + j;
    const bool act = ((m >> j) & 1u) != 0u;
    const unsigned rb = __popc(m & ((1u << j) - 1u));
    const unsigned actsBefore = thread_excl + rb;
    const unsigned dr = act ? actsBefore : (cnt + ((unsigned)li - actsBefore));
    unsigned short rv = sent16, sv = sent16;
    if (act) {
      if (is64) {
        rv = (unsigned short)((const long long*)rec32)[i];
        sv = (unsigned short)((const long long*)send32)[i];
      } else {
        rv = (unsigned short)rec32[i];
        sv = (unsigned short)send32[i];
      }
    }
    s_sidx[dr] = (unsigned short)li;
    s_rec[dr] = rv;
    s_send[dr] = sv;
  }
  __syncthreads();

  const unsigned gA = bsums[blockIdx.x];
  const unsigned nA = bsums[nblocks];
  const unsigned gI = nA + (unsigned)tileBase - gA;

  float* __restrict__ out_na = out;
  float* __restrict__ out_rec = out + (size_t)E;
  float* __restrict__ out_send = out + 2 * (size_t)E;
  float* __restrict__ out_edges = out + 3 * (size_t)E;
  const f4v zero4 = {0.f, 0.f, 0.f, 0.f};
  const int sub = tid & 3;

  if (local_n == TILE) {
    // --- full tile: no breaks, deep ILP ---
#pragma unroll
    for (int k = 0; k < ITEMS; ++k) {
      const int r = tid + k * BLOCK;
      const bool ra = (unsigned)r < cnt;
      const unsigned dest = ra ? (gA + (unsigned)r) : (gI + ((unsigned)r - cnt));
      __builtin_nontemporal_store(ra ? 1.0f : 0.0f, out_na + dest);
      __builtin_nontemporal_store((float)s_rec[r], out_rec + dest);
      __builtin_nontemporal_store((float)s_send[r], out_send + dest);
    }
#pragma unroll 8
    for (int k = 0; k < TILE / (BLOCK / 4); ++k) {  // 32 iters, 4 lanes/row
      const int r = (tid >> 2) + k * (BLOCK / 4);
      const bool ra = (unsigned)r < cnt;
      const unsigned dest = ra ? (gA + (unsigned)r) : (gI + ((unsigned)r - cnt));
      f4v v = zero4;
      if (ra) {
        const int si = (int)s_sidx[r];
        v = ((const f4v*)edges)[(size_t)(tileBase + si) * 4 + sub];
      }
      __builtin_nontemporal_store(v, (f4v*)out_edges + (size_t)dest * 4 + sub);
    }
  } else {
    for (int k = 0; k < ITEMS; ++k) {
      const int r = tid + k * BLOCK;
      if (r >= local_n) break;
      const bool ra = (unsigned)r < cnt;
      const unsigned dest = ra ? (gA + (unsigned)r) : (gI + ((unsigned)r - cnt));
      out_na[dest] = ra ? 1.0f : 0.0f;
      out_rec[dest] = (float)s_rec[r];
      out_send[dest] = (float)s_send[r];
    }
    for (int k = 0; k < TILE / (BLOCK / 4); ++k) {
      const int r = (tid >> 2) + k * (BLOCK / 4);
      if (r >= local_n) break;
      const bool ra = (unsigned)r < cnt;
      const unsigned dest = ra ? (gA + (unsigned)r) : (gI + ((unsigned)r - cnt));
      f4v v = zero4;
      if (ra) {
        const int si = (int)s_sidx[r];
        v = ((const f4v*)edges)[(size_t)(tileBase + si) * 4 + sub];
      }
      ((f4v*)out_edges)[(size_t)dest * 4 + sub] = v;
    }
  }
}

extern "C" void kernel_launch(void* const* d_in, const int* in_sizes, int n_in,
                              void* d_out, int out_size, void* d_ws, size_t ws_size,
                              hipStream_t stream) {
  const float* edges = (const float*)d_in[1];
  const float* aedges = (const float*)d_in[2];
  const float* uw = (const float*)d_in[3];
  const float* ue = (const float*)d_in[4];
  const int* rec = (const int*)d_in[5];
  const int* send = (const int*)d_in[6];
  const int* timep = (const int*)d_in[7];

  const int E = in_sizes[2];
  const int n_nodes = in_sizes[0] / 128;
  const int sentinel = n_nodes - 1;
  const int nblocks = (E + TILE - 1) / TILE;

  unsigned* bsums = (unsigned*)d_ws;                       // nblocks+1 uints
  unsigned* flagp = bsums + (nblocks + 2);                 // dtype flag
  unsigned char* masks = (unsigned char*)(bsums + nblocks + 16);
  const size_t need = (size_t)(nblocks + 16) * 4 + (size_t)nblocks * BLOCK + 64;
  const int use_masks = (ws_size >= need) ? 1 : 0;
  float* out = (float*)d_out;

  hipLaunchKernelGGL(detect_i64, dim3(1), dim3(64), 0, stream,
                     (const unsigned*)rec, (const unsigned*)send, flagp);
  hipLaunchKernelGGL(passA, dim3(nblocks), dim3(BLOCK), 0, stream,
                     aedges, ue, uw, timep, bsums, masks, use_masks, E);
  hipLaunchKernelGGL(passB, dim3(1), dim3(BLOCK), 0, stream, bsums, nblocks);
  hipLaunchKernelGGL(passC, dim3(nblocks), dim3(BLOCK), 0, stream,
                     aedges, ue, uw, timep, rec, send, edges, bsums, nblocks,
                     flagp, masks, use_masks, out, E, sentinel);
}